// Round 1
// baseline (193.595 us; speedup 1.0000x reference)
//
#include <hip/hip_runtime.h>
#include <stdint.h>

typedef unsigned int u32;
typedef unsigned long long u64;
typedef unsigned short u16;
typedef unsigned char u8;

#define NPTS 8192
#define GRIDW 64
#define NCELLS 4096
#define CAP 32
#define RADIUS 8.0f

// ---------------------------------------------------------------------------
// K1: keys (priority), cell ids, cell histogram
// ---------------------------------------------------------------------------
__global__ __launch_bounds__(256) void k_prep(const float* __restrict__ coords,
                                              const float* __restrict__ scores,
                                              u64* __restrict__ key,
                                              u32* __restrict__ cell_of,
                                              u32* __restrict__ cell_count) {
  int i = blockIdx.x * 256 + threadIdx.x;
  if (i >= NPTS) return;
  float x = coords[2 * i + 0];
  float y = coords[2 * i + 1];
  // scores in [0,1): positive floats -> bit pattern is order-preserving.
  // tie-break: smaller original index = higher priority (stable argsort(-s)).
  u32 sb = __float_as_uint(scores[i]);
  key[i] = ((u64)sb << 32) | (u64)(0xFFFFFFFFu - (u32)i);
  int cx = (int)(x * 0.125f); cx = cx < 0 ? 0 : (cx > 63 ? 63 : cx);
  int cy = (int)(y * 0.125f); cy = cy < 0 ? 0 : (cy > 63 ? 63 : cy);
  u32 c = (u32)(cy * GRIDW + cx);
  cell_of[i] = c;
  atomicAdd(&cell_count[c], 1u);
}

// ---------------------------------------------------------------------------
// K2: exclusive scan of 4096 cell counts (single block, 1024 thr, 4 cells ea)
// ---------------------------------------------------------------------------
__global__ __launch_bounds__(1024) void k_scan(const u32* __restrict__ cell_count,
                                               u32* __restrict__ cell_start) {
  __shared__ u32 part[1024];
  int t = threadIdx.x;
  u32 v0 = cell_count[4 * t + 0];
  u32 v1 = cell_count[4 * t + 1];
  u32 v2 = cell_count[4 * t + 2];
  u32 v3 = cell_count[4 * t + 3];
  u32 sum = v0 + v1 + v2 + v3;
  part[t] = sum;
  __syncthreads();
  for (int off = 1; off < 1024; off <<= 1) {
    u32 x = (t >= off) ? part[t - off] : 0u;
    __syncthreads();
    part[t] += x;
    __syncthreads();
  }
  u32 excl = part[t] - sum;  // exclusive prefix of this thread's 4 cells
  cell_start[4 * t + 0] = excl;
  cell_start[4 * t + 1] = excl + v0;
  cell_start[4 * t + 2] = excl + v0 + v1;
  cell_start[4 * t + 3] = excl + v0 + v1 + v2;
}

// ---------------------------------------------------------------------------
// K3: scatter point ids into cell-sorted array
// ---------------------------------------------------------------------------
__global__ __launch_bounds__(256) void k_scatter(const u32* __restrict__ cell_of,
                                                 const u32* __restrict__ cell_start,
                                                 u32* __restrict__ cell_cursor,
                                                 u32* __restrict__ cell_pts) {
  int i = blockIdx.x * 256 + threadIdx.x;
  if (i >= NPTS) return;
  u32 c = cell_of[i];
  u32 slot = atomicAdd(&cell_cursor[c], 1u);
  cell_pts[cell_start[c] + slot] = (u32)i;
}

// ---------------------------------------------------------------------------
// K4: per point, collect HIGHER-PRIORITY neighbors within radius (3x3 cells)
// ---------------------------------------------------------------------------
__global__ __launch_bounds__(256) void k_nbr(const float* __restrict__ coords,
                                             const u64* __restrict__ key,
                                             const u32* __restrict__ cell_of,
                                             const u32* __restrict__ cell_start,
                                             const u32* __restrict__ cell_count,
                                             const u32* __restrict__ cell_pts,
                                             u32* __restrict__ nbr_cnt,
                                             u16* __restrict__ nbr_idx) {
  int i = blockIdx.x * 256 + threadIdx.x;
  if (i >= NPTS) return;
  float x = coords[2 * i + 0];
  float y = coords[2 * i + 1];
  u64 ki = key[i];
  int c = (int)cell_of[i];
  int cx = c & 63;
  int cy = c >> 6;
  u32 cnt = 0;
  u16* row = nbr_idx + (size_t)i * CAP;
  for (int dy = -1; dy <= 1; ++dy) {
    int yy = cy + dy;
    if (yy < 0 || yy > 63) continue;
    for (int dxc = -1; dxc <= 1; ++dxc) {
      int xx = cx + dxc;
      if (xx < 0 || xx > 63) continue;
      int cc = yy * GRIDW + xx;
      u32 s = cell_start[cc];
      u32 n = cell_count[cc];
      for (u32 p = 0; p < n; ++p) {
        u32 j = cell_pts[s + p];
        if (key[j] > ki) {  // j strictly higher priority (keys unique)
          // exactly mirror reference arithmetic: mul, mul, add, sqrt, cmp —
          // no FMA contraction (a boundary flip = absmax 1.0)
          float dx = __fsub_rn(x, coords[2 * j + 0]);
          float dyv = __fsub_rn(y, coords[2 * j + 1]);
          float d2 = __fadd_rn(__fmul_rn(dx, dx), __fmul_rn(dyv, dyv));
          float dist = __fsqrt_rn(d2);
          if (dist < RADIUS) {
            if (cnt < CAP) row[cnt] = (u16)j;
            cnt++;
          }
        }
      }
    }
  }
  nbr_cnt[i] = cnt < CAP ? cnt : CAP;  // P(overflow) ~ 1e-15 at lambda=6.3
}

// ---------------------------------------------------------------------------
// K5: rank[i] = #{j : key_j > key_i}  (position in descending stable sort)
// 512 blocks x 256: p = gid&8191 (coalesced), chunk c = gid>>13 (uniform
// inner address -> broadcast loads from L2)
// ---------------------------------------------------------------------------
__global__ __launch_bounds__(256) void k_rank(const u64* __restrict__ key,
                                              u32* __restrict__ rank) {
  int gid = blockIdx.x * 256 + threadIdx.x;
  int p = gid & (NPTS - 1);
  int c = gid >> 13;  // 0..15
  u64 kp = key[p];
  const u64* base = key + c * 512;
  u32 cnt = 0;
#pragma unroll 8
  for (int t = 0; t < 512; ++t) cnt += (base[t] > kp) ? 1u : 0u;
  if (cnt) atomicAdd(&rank[p], cnt);
}

// ---------------------------------------------------------------------------
// K6: greedy-NMS fixpoint (single block, LDS keep flags) + output epilogue
//   keep[i] <=> no higher-priority neighbor j with keep[j]
// Unique solution of a DAG recursion; chaotic iteration converges in
// DAG-depth rounds (~25 expected here). Convergence => exact greedy result.
// ---------------------------------------------------------------------------
__global__ __launch_bounds__(1024) void k_nms(const u32* __restrict__ nbr_cnt,
                                              const u16* __restrict__ nbr_idx,
                                              const u32* __restrict__ rank,
                                              const float* __restrict__ scores,
                                              float* __restrict__ out) {
  __shared__ u8 keep[NPTS];
  __shared__ int changed;
  int t = threadIdx.x;
  for (int k = t; k < NPTS; k += 1024) keep[k] = 1;
  if (t == 0) changed = 0;
  __syncthreads();

  for (int round = 0; round < NPTS + 8; ++round) {
    // work phase: re-evaluate my 8 points against current flags
    for (int k = 0; k < 8; ++k) {
      int i = t + k * 1024;
      u32 cnt = nbr_cnt[i];
      const u16* row = nbr_idx + (size_t)i * CAP;
      bool alive = true;
      for (u32 n = 0; n < cnt; ++n) {
        if (keep[row[n]]) { alive = false; break; }
      }
      u8 a = alive ? (u8)1 : (u8)0;
      if (keep[i] != a) {
        keep[i] = a;       // byte write, each point owned by one thread
        changed = 1;       // benign race, all writers store 1
      }
    }
    __syncthreads();
    int c = changed;       // read between barriers -> uniform across block
    __syncthreads();
    if (!c) break;
    if (t == 0) changed = 0;
    __syncthreads();
  }

  // epilogue: keep mask in original order + suppressed scores in sorted order
  for (int k = t; k < NPTS; k += 1024) {
    u8 kp = keep[k];
    out[k] = kp ? 1.0f : 0.0f;
    out[NPTS + rank[k]] = kp ? scores[k] : 0.0f;
  }
}

// ---------------------------------------------------------------------------
extern "C" void kernel_launch(void* const* d_in, const int* in_sizes, int n_in,
                              void* d_out, int out_size, void* d_ws, size_t ws_size,
                              hipStream_t stream) {
  const float* coords = (const float*)d_in[0];  // [N,2]
  const float* scores = (const float*)d_in[1];  // [N]
  float* out = (float*)d_out;                   // [N keep | N suppressed scores]

  char* ws = (char*)d_ws;
  size_t off = 0;
  u64* key        = (u64*)(ws + off); off += (size_t)NPTS * 8;        // 64K
  u16* nbr_idx    = (u16*)(ws + off); off += (size_t)NPTS * CAP * 2;  // 512K
  u32* cell_of    = (u32*)(ws + off); off += (size_t)NPTS * 4;        // 32K
  u32* cell_start = (u32*)(ws + off); off += (size_t)NCELLS * 4;      // 16K
  u32* cell_pts   = (u32*)(ws + off); off += (size_t)NPTS * 4;        // 32K
  u32* nbr_cnt    = (u32*)(ws + off); off += (size_t)NPTS * 4;        // 32K
  // zeroed region (one memset): cell_count | cell_cursor | rank
  char* zbase = ws + off;
  u32* cell_count  = (u32*)(ws + off); off += (size_t)NCELLS * 4;     // 16K
  u32* cell_cursor = (u32*)(ws + off); off += (size_t)NCELLS * 4;     // 16K
  u32* rank        = (u32*)(ws + off); off += (size_t)NPTS * 4;       // 32K
  size_t zbytes = (size_t)NCELLS * 4 + (size_t)NCELLS * 4 + (size_t)NPTS * 4;

  hipMemsetAsync(zbase, 0, zbytes, stream);

  dim3 b256(256), g32(NPTS / 256);
  k_prep<<<g32, b256, 0, stream>>>(coords, scores, key, cell_of, cell_count);
  k_scan<<<1, 1024, 0, stream>>>(cell_count, cell_start);
  k_scatter<<<g32, b256, 0, stream>>>(cell_of, cell_start, cell_cursor, cell_pts);
  k_nbr<<<g32, b256, 0, stream>>>(coords, key, cell_of, cell_start, cell_count,
                                  cell_pts, nbr_cnt, nbr_idx);
  k_rank<<<(NPTS * 16) / 256, b256, 0, stream>>>(key, rank);
  k_nms<<<1, 1024, 0, stream>>>(nbr_cnt, nbr_idx, rank, scores, out);
}

// Round 2
// 157.345 us; speedup vs baseline: 1.2304x; 1.2304x over previous
//
#include <hip/hip_runtime.h>
#include <stdint.h>

typedef unsigned int u32;
typedef unsigned long long u64;
typedef unsigned short u16;
typedef unsigned char u8;

#define NPTS 8192
#define GRIDW 64
#define NCELLS 4096
#define CAP 32
#define SEG 1024
#define NSEG 8

// ---------------------------------------------------------------------------
// K1: priority keys, cell ids, cell histogram
// ---------------------------------------------------------------------------
__global__ __launch_bounds__(256) void k_prep(const float* __restrict__ coords,
                                              const float* __restrict__ scores,
                                              u64* __restrict__ key,
                                              u32* __restrict__ cell_of,
                                              u32* __restrict__ cell_count) {
  int i = blockIdx.x * 256 + threadIdx.x;
  if (i >= NPTS) return;
  float x = coords[2 * i + 0];
  float y = coords[2 * i + 1];
  // scores in [0,1): positive floats -> bit pattern order-preserving.
  // tie-break: smaller index = higher priority (stable argsort(-s)).
  u32 sb = __float_as_uint(scores[i]);
  key[i] = ((u64)sb << 32) | (u64)(0xFFFFFFFFu - (u32)i);
  int cx = (int)(x * 0.125f); cx = cx < 0 ? 0 : (cx > 63 ? 63 : cx);
  int cy = (int)(y * 0.125f); cy = cy < 0 ? 0 : (cy > 63 ? 63 : cy);
  u32 c = (u32)(cy * GRIDW + cx);
  cell_of[i] = c;
  atomicAdd(&cell_count[c], 1u);
}

// ---------------------------------------------------------------------------
// K2: rank[i] = #{j : key_j > key_i}  (position in descending stable sort)
// p = gid&8191 coalesced; chunk c uniform per wave -> scalarizable loads
// ---------------------------------------------------------------------------
__global__ __launch_bounds__(256) void k_rank(const u64* __restrict__ key,
                                              u32* __restrict__ rank) {
  int gid = blockIdx.x * 256 + threadIdx.x;
  int p = gid & (NPTS - 1);
  int c = gid >> 13;  // 0..15
  u64 kp = key[p];
  const u64* base = key + c * 512;
  u32 cnt = 0;
#pragma unroll 8
  for (int t = 0; t < 512; ++t) cnt += (base[t] > kp) ? 1u : 0u;
  if (cnt) atomicAdd(&rank[p], cnt);
}

// ---------------------------------------------------------------------------
// K3: exclusive scan of 4096 cell counts
// ---------------------------------------------------------------------------
__global__ __launch_bounds__(1024) void k_scan(const u32* __restrict__ cell_count,
                                               u32* __restrict__ cell_start) {
  __shared__ u32 part[1024];
  int t = threadIdx.x;
  u32 v0 = cell_count[4 * t + 0];
  u32 v1 = cell_count[4 * t + 1];
  u32 v2 = cell_count[4 * t + 2];
  u32 v3 = cell_count[4 * t + 3];
  u32 sum = v0 + v1 + v2 + v3;
  part[t] = sum;
  __syncthreads();
  for (int off = 1; off < 1024; off <<= 1) {
    u32 x = (t >= off) ? part[t - off] : 0u;
    __syncthreads();
    part[t] += x;
    __syncthreads();
  }
  u32 excl = part[t] - sum;
  cell_start[4 * t + 0] = excl;
  cell_start[4 * t + 1] = excl + v0;
  cell_start[4 * t + 2] = excl + v0 + v1;
  cell_start[4 * t + 3] = excl + v0 + v1 + v2;
}

// ---------------------------------------------------------------------------
// K4: scatter into rank space: cell lists hold RANKS; sorted copies of
// coords/scores/cell so everything downstream is rank-indexed.
// ---------------------------------------------------------------------------
__global__ __launch_bounds__(256) void k_scatter(const float* __restrict__ coords,
                                                 const float* __restrict__ scores,
                                                 const u32* __restrict__ cell_of,
                                                 const u32* __restrict__ cell_start,
                                                 const u32* __restrict__ rank,
                                                 u32* __restrict__ cell_cursor,
                                                 u16* __restrict__ cell_pts,
                                                 u32* __restrict__ sorted_id,
                                                 float* __restrict__ sx,
                                                 float* __restrict__ sy,
                                                 float* __restrict__ ss,
                                                 u16* __restrict__ scell) {
  int i = blockIdx.x * 256 + threadIdx.x;
  if (i >= NPTS) return;
  u32 c = cell_of[i];
  u32 r = rank[i];
  u32 slot = atomicAdd(&cell_cursor[c], 1u);
  cell_pts[cell_start[c] + slot] = (u16)r;
  sorted_id[r] = (u32)i;
  sx[r] = coords[2 * i + 0];  // bitwise copies -> arithmetic stays exact
  sy[r] = coords[2 * i + 1];
  ss[r] = scores[i];
  scell[r] = (u16)c;
}

// ---------------------------------------------------------------------------
// K5: per (rank, one-of-9-cells): collect higher-priority (lower-rank)
// in-radius neighbors. Column-major nbr[slot*NPTS + r] -> coalesced.
// Grid: 9 cells x 32 blocks of 256 ranks.
// ---------------------------------------------------------------------------
__global__ __launch_bounds__(256) void k_nbr(const float* __restrict__ sx,
                                             const float* __restrict__ sy,
                                             const u16* __restrict__ scell,
                                             const u32* __restrict__ cell_start,
                                             const u32* __restrict__ cell_count,
                                             const u16* __restrict__ cell_pts,
                                             u32* __restrict__ nbr_cnt,
                                             u16* __restrict__ nbr) {
  int kk = blockIdx.x >> 5;                           // 0..8 (uniform per block)
  int r  = ((blockIdx.x & 31) << 8) + threadIdx.x;    // 0..8191
  int dxc = kk % 3 - 1;
  int dyc = kk / 3 - 1;
  float x = sx[r], y = sy[r];
  int c = scell[r];
  int cx = (c & 63) + dxc;
  int cy = (c >> 6) + dyc;
  if (cx < 0 || cx > 63 || cy < 0 || cy > 63) return;
  int cc = cy * GRIDW + cx;
  u32 s = cell_start[cc];
  u32 n = cell_count[cc];
  for (u32 p = 0; p < n; ++p) {
    u32 q = cell_pts[s + p];
    if ((int)q < r) {  // strictly higher priority
      // mirror reference arithmetic exactly: sub, mul, mul, add, sqrt, cmp
      float ddx = __fsub_rn(x, sx[q]);
      float ddy = __fsub_rn(y, sy[q]);
      float d2 = __fadd_rn(__fmul_rn(ddx, ddx), __fmul_rn(ddy, ddy));
      if (__fsqrt_rn(d2) < 8.0f) {
        u32 sl = atomicAdd(&nbr_cnt[r], 1u);
        if (sl < CAP) nbr[(size_t)sl * NPTS + r] = (u16)q;
      }
    }
  }
}

// ---------------------------------------------------------------------------
// K6: segmented Gauss-Seidel greedy fixpoint in rank space.
// 8 segments of 1024 ranks; prefix segments final when a segment starts, so
// only intra-segment edges (in-degree ~0.4) need Jacobi rounds (~3-5).
// 4-slot rotating changed-flag: 1 barrier/round. Reset of slot[r%4] happens
// at round r+2 -> after all round-r readers passed round-(r+1)'s barrier.
// ---------------------------------------------------------------------------
__global__ __launch_bounds__(1024) void k_nms(const u32* __restrict__ nbr_cnt,
                                              const u16* __restrict__ nbr,
                                              const u32* __restrict__ sorted_id,
                                              const float* __restrict__ ss,
                                              float* __restrict__ out) {
  __shared__ u8 keep[NPTS];
  __shared__ int slot[4];
  int t = threadIdx.x;

  for (int s = 0; s < NSEG; ++s) {
    int segbase = s << 10;
    int p = segbase + t;
    u32 cnt = nbr_cnt[p];
    if (cnt > CAP) cnt = CAP;
    const u16* row = nbr + p;  // element n at row[n*NPTS]
    keep[p] = 1;
    if (t < 4) slot[t] = 0;    // benign 0-over-0 race vs prev segment's exit read
    __syncthreads();

    bool active = true;  // resolved in round 0
    for (int r = 0; r < SEG + 2; ++r) {
      if (t == 0) slot[(r + 2) & 3] = 0;
      bool flip = false;
      if (r == 0) {
        // full evaluation + classify: inactive if final after this round
        bool alive = true, sawInseg = false;
        for (u32 n2 = 0; n2 < cnt; ++n2) {
          u32 q = row[(size_t)n2 * NPTS];
          if (keep[q]) {
            alive = false;
            // kept prefix nbr -> permanently suppressed; kept in-seg -> may flip
            active = (q >= (u32)segbase);
            break;
          }
          if (q >= (u32)segbase) sawInseg = true;
        }
        if (alive) active = sawInseg;  // no in-seg deps -> final
        u8 a = alive ? (u8)1 : (u8)0;
        if (keep[p] != a) { keep[p] = a; flip = true; }
      } else if (active) {
        bool alive = true;
        for (u32 n2 = 0; n2 < cnt; ++n2) {
          u32 q = row[(size_t)n2 * NPTS];
          if (keep[q]) { alive = false; break; }
        }
        u8 a = alive ? (u8)1 : (u8)0;
        if (keep[p] != a) { keep[p] = a; flip = true; }
      }
      if (flip) slot[r & 3] = 1;
      __syncthreads();
      if (slot[r & 3] == 0) break;  // uniform: value stable in read window
    }
  }

  // epilogue: keep mask in original order + suppressed scores in rank order
  for (int k = t; k < NPTS; k += 1024) {
    u8 kp = keep[k];
    out[sorted_id[k]] = kp ? 1.0f : 0.0f;
    out[NPTS + k] = kp ? ss[k] : 0.0f;
  }
}

// ---------------------------------------------------------------------------
extern "C" void kernel_launch(void* const* d_in, const int* in_sizes, int n_in,
                              void* d_out, int out_size, void* d_ws, size_t ws_size,
                              hipStream_t stream) {
  const float* coords = (const float*)d_in[0];  // [N,2]
  const float* scores = (const float*)d_in[1];  // [N]
  float* out = (float*)d_out;                   // [N keep | N suppressed scores]

  char* ws = (char*)d_ws;
  size_t off = 0;
  u64* key        = (u64*)(ws + off); off += (size_t)NPTS * 8;             // 64K
  u16* nbr        = (u16*)(ws + off); off += (size_t)CAP * NPTS * 2;       // 512K
  u32* cell_of    = (u32*)(ws + off); off += (size_t)NPTS * 4;             // 32K
  u32* cell_start = (u32*)(ws + off); off += (size_t)NCELLS * 4;           // 16K
  u16* cell_pts   = (u16*)(ws + off); off += (size_t)NPTS * 2;             // 16K
  u32* sorted_id  = (u32*)(ws + off); off += (size_t)NPTS * 4;             // 32K
  float* sx       = (float*)(ws + off); off += (size_t)NPTS * 4;           // 32K
  float* sy       = (float*)(ws + off); off += (size_t)NPTS * 4;           // 32K
  float* ss       = (float*)(ws + off); off += (size_t)NPTS * 4;           // 32K
  u16* scell      = (u16*)(ws + off); off += (size_t)NPTS * 2;             // 16K
  // zeroed region (single memset): cell_count | cell_cursor | rank | nbr_cnt
  char* zbase = ws + off;
  u32* cell_count  = (u32*)(ws + off); off += (size_t)NCELLS * 4;          // 16K
  u32* cell_cursor = (u32*)(ws + off); off += (size_t)NCELLS * 4;          // 16K
  u32* rank        = (u32*)(ws + off); off += (size_t)NPTS * 4;            // 32K
  u32* nbr_cnt     = (u32*)(ws + off); off += (size_t)NPTS * 4;            // 32K
  size_t zbytes = (size_t)NCELLS * 8 + (size_t)NPTS * 8;                   // 96K

  hipMemsetAsync(zbase, 0, zbytes, stream);

  dim3 b256(256), g32(NPTS / 256);
  k_prep<<<g32, b256, 0, stream>>>(coords, scores, key, cell_of, cell_count);
  k_rank<<<(NPTS * 16) / 256, b256, 0, stream>>>(key, rank);
  k_scan<<<1, 1024, 0, stream>>>(cell_count, cell_start);
  k_scatter<<<g32, b256, 0, stream>>>(coords, scores, cell_of, cell_start, rank,
                                      cell_cursor, cell_pts, sorted_id, sx, sy, ss, scell);
  k_nbr<<<9 * 32, b256, 0, stream>>>(sx, sy, scell, cell_start, cell_count,
                                     cell_pts, nbr_cnt, nbr);
  k_nms<<<1, 1024, 0, stream>>>(nbr_cnt, nbr, sorted_id, ss, out);
}